// Round 5
// baseline (5354.882 us; speedup 1.0000x reference)
//
#include <hip/hip_runtime.h>
#include <math.h>

// Problem constants: T=64, B=1024, H=512, V=512
constexpr int T_STEPS = 64;
constexpr int B_SZ = 1024;
constexpr int H_SZ = 512;
constexpr int V_SZ = 512;
constexpr int G_SZ = 4 * H_SZ; // 2048
constexpr int N_BLOCKS = 256;

typedef _Float16 half8 __attribute__((ext_vector_type(8)));
typedef _Float16 half4 __attribute__((ext_vector_type(4)));
typedef float f32x4 __attribute__((ext_vector_type(4)));

__device__ __forceinline__ float4 ld4(const float* p) {
    return *reinterpret_cast<const float4*>(p);
}
__device__ __forceinline__ void st4(float* p, float4 v) {
    *reinterpret_cast<float4*>(p) = v;
}
__device__ __forceinline__ float sigf(float x) { return 1.f / (1.f + expf(-x)); }

// packed argmax word: high 32 = orderable float key, low 32 = (511 - col)
__device__ __forceinline__ unsigned long long pack_vc(float v, int col) {
    unsigned u = __float_as_uint(v);
    unsigned key = (u & 0x80000000u) ? ~u : (u | 0x80000000u);
    return ((unsigned long long)key << 32) | (unsigned)(511 - col);
}

// hand-rolled grid barrier (sense via monotonically increasing generation)
__device__ __forceinline__ void grid_barrier(unsigned* cnt, unsigned* gen) {
    __syncthreads(); // intra-block: all threads' writes ordered before arrive
    if (threadIdx.x == 0) {
        const unsigned g = __hip_atomic_load(gen, __ATOMIC_RELAXED,
                                             __HIP_MEMORY_SCOPE_AGENT);
        const unsigned arrived = __hip_atomic_fetch_add(
            cnt, 1u, __ATOMIC_ACQ_REL, __HIP_MEMORY_SCOPE_AGENT) + 1u;
        if (arrived == (unsigned)N_BLOCKS) {
            __hip_atomic_store(cnt, 0u, __ATOMIC_RELAXED,
                               __HIP_MEMORY_SCOPE_AGENT);
            __hip_atomic_fetch_add(gen, 1u, __ATOMIC_RELEASE,
                                   __HIP_MEMORY_SCOPE_AGENT);
        } else {
            while (__hip_atomic_load(gen, __ATOMIC_ACQUIRE,
                                     __HIP_MEMORY_SCOPE_AGENT) == g)
                __builtin_amdgcn_s_sleep(2);
        }
    }
    __syncthreads(); // all threads wait for thread 0's acquire
}

// ---------------------------------------------------------------------------
// fp32 -> (hi fp16, lo fp16) split: x ~= hi + lo/2048
// ---------------------------------------------------------------------------
__global__ __launch_bounds__(256) void cvt_pair(
    const float* __restrict__ x, _Float16* __restrict__ hi,
    _Float16* __restrict__ lo)
{
    const int i4 = blockIdx.x * 256 + threadIdx.x;
    const float4 v = ld4(x + (size_t)i4 * 4);
    half4 h, l;
    const float h0 = (float)(_Float16)v.x; h[0] = (_Float16)v.x; l[0] = (_Float16)((v.x - h0) * 2048.f);
    const float h1 = (float)(_Float16)v.y; h[1] = (_Float16)v.y; l[1] = (_Float16)((v.y - h1) * 2048.f);
    const float h2 = (float)(_Float16)v.z; h[2] = (_Float16)v.z; l[2] = (_Float16)((v.z - h2) * 2048.f);
    const float h3 = (float)(_Float16)v.w; h[3] = (_Float16)v.w; l[3] = (_Float16)((v.w - h3) * 2048.f);
    *reinterpret_cast<half4*>(hi + (size_t)i4 * 4) = h;
    *reinterpret_cast<half4*>(lo + (size_t)i4 * 4) = l;
}

// ---------------------------------------------------------------------------
// fp32 tiled NT GEMM — used once for E_gates = emb @ W_ih^T + (b_ih+b_hh)
// ---------------------------------------------------------------------------
__global__ __launch_bounds__(256) void gemm_nt_f32(
    const float* __restrict__ A, const float* __restrict__ Bw,
    float* __restrict__ C, int M, int N, int K,
    const float* __restrict__ bias1, const float* __restrict__ bias2)
{
    constexpr int BK = 16;
    __shared__ __align__(16) float As[BK][64];
    __shared__ __align__(16) float Bs[BK][64];
    const int tid = threadIdx.x;
    const int tx = tid % 16, ty = tid / 16;
    const int m0 = blockIdx.y * 64, n0 = blockIdx.x * 64;
    const int lr = tid / 4, lc = (tid % 4) * 4;
    float acc[4][4] = {};
    for (int k0 = 0; k0 < K; k0 += BK) {
        const float4 av = ld4(&A[(size_t)(m0 + lr) * K + (k0 + lc)]);
        const float4 bv = ld4(&Bw[(size_t)(n0 + lr) * K + (k0 + lc)]);
        __syncthreads();
        As[lc + 0][lr] = av.x; As[lc + 1][lr] = av.y; As[lc + 2][lr] = av.z; As[lc + 3][lr] = av.w;
        Bs[lc + 0][lr] = bv.x; Bs[lc + 1][lr] = bv.y; Bs[lc + 2][lr] = bv.z; Bs[lc + 3][lr] = bv.w;
        __syncthreads();
#pragma unroll
        for (int k = 0; k < BK; ++k) {
            const float4 a4 = ld4(&As[k][ty * 4]);
            const float4 b4 = ld4(&Bs[k][tx * 4]);
            const float ar[4] = {a4.x, a4.y, a4.z, a4.w};
            const float br[4] = {b4.x, b4.y, b4.z, b4.w};
#pragma unroll
            for (int i = 0; i < 4; ++i)
#pragma unroll
                for (int j = 0; j < 4; ++j)
                    acc[i][j] = fmaf(ar[i], br[j], acc[i][j]);
        }
    }
    const int nc = n0 + tx * 4;
    const float4 b1 = ld4(&bias1[nc]);
    const float4 b2 = ld4(&bias2[nc]);
#pragma unroll
    for (int i = 0; i < 4; ++i) {
        const int m = m0 + ty * 4 + i;
        float4 v;
        v.x = acc[i][0] + b1.x + b2.x; v.y = acc[i][1] + b1.y + b2.y;
        v.z = acc[i][2] + b1.z + b2.z; v.w = acc[i][3] + b1.w + b2.w;
        st4(&C[(size_t)m * N + nc], v);
    }
}

// init token buffers + barrier state (re-run every launch; graph-replay safe)
__global__ __launch_bounds__(256) void init_state(
    unsigned long long* __restrict__ tok, unsigned* __restrict__ bar)
{
    const int i = blockIdx.x * 256 + threadIdx.x; // 0..2047
    tok[i] = (i < 1024) ? 511ULL : 0ULL; // buf0: token 0 (SOS); buf1: cleared
    if (i < 2) bar[i] = 0u;              // count, generation
}

// ---------------------------------------------------------------------------
// Persistent kernel: all 64 steps. Grid 256 blocks x 256 threads (1 blk/CU).
// Per step: phase 1 (gates MFMA + cell) | barrier | phase 2 (logits + argmax)
// | barrier.
// ---------------------------------------------------------------------------
__global__ __launch_bounds__(256, 1) void persistent_decoder(
    const _Float16* __restrict__ Whh_hi, const _Float16* __restrict__ Whh_lo,
    const _Float16* __restrict__ Wout_hi, const _Float16* __restrict__ Wout_lo,
    const float* __restrict__ Eg, const float* __restrict__ b_out,
    _Float16* __restrict__ H0hi, _Float16* __restrict__ H0lo,
    _Float16* __restrict__ H1hi, _Float16* __restrict__ H1lo,
    float* __restrict__ cbuf, unsigned long long* __restrict__ tokbuf,
    unsigned* __restrict__ bar, float* __restrict__ out)
{
    constexpr int LDK = 40; // padded LDS row in halves (80B)
    __shared__ __align__(16) char smem[64 * 129 * 4]; // 33024 B
    _Float16* sAh = (_Float16*)smem;            // 64*40
    _Float16* sAl = sAh + 64 * LDK;
    _Float16* sBh = sAl + 64 * LDK;             // 128*40
    _Float16* sBl = sBh + 128 * LDK;
    float* sg = (float*)smem;                   // 64 x 129 (repurposed)

    unsigned* bar_cnt = bar;
    unsigned* bar_gen = bar + 1;

    const int bid = blockIdx.x;
    const int tid = threadIdx.x;
    const int wave = tid >> 6, lane = tid & 63;
    const int lm = lane & 15, kq = lane >> 4;

    // ---- phase-1 block/thread constants
    const int wm = wave >> 1, wn = wave & 1;
    const int h0 = (bid & 15) * 32;
    const int b0 = (bid >> 4) * 64;
    const int ar = tid >> 2, akc = (tid & 3) * 8;
    const int r2 = ar + 64;
    const int g1 = (ar >> 5) * 512 + h0 + (ar & 31);
    const int g2 = (r2 >> 5) * 512 + h0 + (r2 & 31);
    const _Float16* pB1h = Whh_hi + (size_t)g1 * 512 + akc;
    const _Float16* pB1l = Whh_lo + (size_t)g1 * 512 + akc;
    const _Float16* pB2h = Whh_hi + (size_t)g2 * 512 + akc;
    const _Float16* pB2l = Whh_lo + (size_t)g2 * 512 + akc;
    const int crow = tid >> 2;       // cell phase row 0..63
    const int hb = (tid & 3) * 8;

    // ---- phase-2 block/thread constants
    const int wm2 = wave >> 1, wn2 = wave & 1;
    const int m0_2 = (bid >> 3) * 32 + wm2 * 16;
    const int n0_2 = (bid & 7) * 64 + wn2 * 32;
    const size_t wo0 = (size_t)(n0_2 + lm) * 512 + kq * 8;
    const size_t wo1 = (size_t)(n0_2 + 16 + lm) * 512 + kq * 8;
    const float bo0 = b_out[n0_2 + lm];
    const float bo1 = b_out[n0_2 + 16 + lm];

    for (int t = 0; t < T_STEPS; ++t) {
        const _Float16* Ahi = (t & 1) ? H1hi : H0hi;
        const _Float16* Alo = (t & 1) ? H1lo : H0lo;
        _Float16* Nhi = (t & 1) ? H0hi : H1hi;
        _Float16* Nlo = (t & 1) ? H0lo : H1lo;
        const unsigned long long* tok_cur = tokbuf + (t & 1) * B_SZ;
        unsigned long long* tok_nxt = tokbuf + ((t + 1) & 1) * B_SZ;

        // ================= phase 1: gates GEMM + cell =================
        {
            const _Float16* pAh = Ahi + (size_t)(b0 + ar) * 512 + akc;
            const _Float16* pAl = Alo + (size_t)(b0 + ar) * 512 + akc;
            f32x4 aH[2][4] = {};
            f32x4 aC[2][4] = {};
            half8 va_h = *(const half8*)(pAh);
            half8 va_l = *(const half8*)(pAl);
            half8 vb1h = *(const half8*)(pB1h);
            half8 vb1l = *(const half8*)(pB1l);
            half8 vb2h = *(const half8*)(pB2h);
            half8 vb2l = *(const half8*)(pB2l);

            for (int it = 0; it < 16; ++it) {
                __syncthreads(); // previous iteration's LDS reads complete
                *(half8*)(sAh + ar * LDK + akc) = va_h;
                *(half8*)(sAl + ar * LDK + akc) = va_l;
                *(half8*)(sBh + ar * LDK + akc) = vb1h;
                *(half8*)(sBl + ar * LDK + akc) = vb1l;
                *(half8*)(sBh + r2 * LDK + akc) = vb2h;
                *(half8*)(sBl + r2 * LDK + akc) = vb2l;
                __syncthreads();

                // prefetch next K-chunk (wraps to 0 on last iter; unused)
                const int kn = ((it + 1) & 15) * 32;
                va_h = *(const half8*)(pAh + kn);
                va_l = *(const half8*)(pAl + kn);
                vb1h = *(const half8*)(pB1h + kn);
                vb1l = *(const half8*)(pB1l + kn);
                vb2h = *(const half8*)(pB2h + kn);
                vb2l = *(const half8*)(pB2l + kn);

                half8 bh[4], bl[4];
#pragma unroll
                for (int gn = 0; gn < 4; ++gn) {
                    const int rr = wn * 64 + gn * 16 + lm;
                    bh[gn] = *(const half8*)(sBh + rr * LDK + kq * 8);
                    bl[gn] = *(const half8*)(sBl + rr * LDK + kq * 8);
                }
#pragma unroll
                for (int gm = 0; gm < 2; ++gm) {
                    const int rm = wm * 32 + gm * 16 + lm;
                    const half8 ah = *(const half8*)(sAh + rm * LDK + kq * 8);
                    const half8 al = *(const half8*)(sAl + rm * LDK + kq * 8);
#pragma unroll
                    for (int gn = 0; gn < 4; ++gn)
                        aH[gm][gn] = __builtin_amdgcn_mfma_f32_16x16x32_f16(ah, bh[gn], aH[gm][gn], 0, 0, 0);
#pragma unroll
                    for (int gn = 0; gn < 4; ++gn)
                        aC[gm][gn] = __builtin_amdgcn_mfma_f32_16x16x32_f16(ah, bl[gn], aC[gm][gn], 0, 0, 0);
#pragma unroll
                    for (int gn = 0; gn < 4; ++gn)
                        aC[gm][gn] = __builtin_amdgcn_mfma_f32_16x16x32_f16(al, bh[gn], aC[gm][gn], 0, 0, 0);
                }
            }

            __syncthreads(); // staging reads done; repurpose smem as sg
#pragma unroll
            for (int gm = 0; gm < 2; ++gm) {
#pragma unroll
                for (int gn = 0; gn < 4; ++gn) {
                    const int row = wm * 32 + gm * 16 + kq * 4;
                    const int col = wn * 64 + gn * 16 + lm;
#pragma unroll
                    for (int r = 0; r < 4; ++r)
                        sg[(row + r) * 129 + col] =
                            aH[gm][gn][r] + aC[gm][gn][r] * (1.f / 2048.f);
                }
            }
            __syncthreads();

            // cell phase
            const int b = b0 + crow;
            const unsigned long long pk = tok_cur[b];
            const int tk = 511 - (int)(unsigned)(pk & 0xFFFFFFFFu);
            const float* egp = Eg + (size_t)tk * G_SZ + h0;

#pragma unroll
            for (int q = 0; q < 2; ++q) {
                const int hh = hb + q * 4;
                const float* sr = sg + crow * 129;
                const float4 gI = ld4(sr + hh);
                const float4 gF = ld4(sr + 32 + hh);
                const float4 gG = ld4(sr + 64 + hh);
                const float4 gO = ld4(sr + 96 + hh);
                const float4 eI = ld4(egp + hh);
                const float4 eF = ld4(egp + 512 + hh);
                const float4 eG = ld4(egp + 1024 + hh);
                const float4 eO = ld4(egp + 1536 + hh);
                const size_t ci = (size_t)b * 512 + h0 + hh;
                const float4 cv = ld4(cbuf + ci);

                const float iv[4] = {gI.x + eI.x, gI.y + eI.y, gI.z + eI.z, gI.w + eI.w};
                const float fv[4] = {gF.x + eF.x, gF.y + eF.y, gF.z + eF.z, gF.w + eF.w};
                const float gv[4] = {gG.x + eG.x, gG.y + eG.y, gG.z + eG.z, gG.w + eG.w};
                const float ov[4] = {gO.x + eO.x, gO.y + eO.y, gO.z + eO.z, gO.w + eO.w};
                float cc[4] = {cv.x, cv.y, cv.z, cv.w};
                float hn[4];
#pragma unroll
                for (int j = 0; j < 4; ++j) {
                    const float cn = sigf(fv[j]) * cc[j] + sigf(iv[j]) * tanhf(gv[j]);
                    cc[j] = cn;
                    hn[j] = sigf(ov[j]) * tanhf(cn);
                }
                st4(cbuf + ci, make_float4(cc[0], cc[1], cc[2], cc[3]));
                half4 h, l;
#pragma unroll
                for (int j = 0; j < 4; ++j) {
                    const _Float16 hi = (_Float16)hn[j];
                    h[j] = hi;
                    l[j] = (_Float16)((hn[j] - (float)hi) * 2048.f);
                }
                *reinterpret_cast<half4*>(Nhi + ci) = h;
                *reinterpret_cast<half4*>(Nlo + ci) = l;
            }

            if ((bid & 15) == 0 && tid < 64) tok_nxt[b0 + tid] = 0ULL;
        }

        grid_barrier(bar_cnt, bar_gen);

        // ================= phase 2: logits + argmax + out =================
        {
            f32x4 aH[2] = {};
            f32x4 aC[2] = {};
            const _Float16* pA2h = Nhi + (size_t)(m0_2 + lm) * 512 + kq * 8;
            const _Float16* pA2l = Nlo + (size_t)(m0_2 + lm) * 512 + kq * 8;
#pragma unroll 2
            for (int k0 = 0; k0 < 512; k0 += 32) {
                const half8 ah = *(const half8*)(pA2h + k0);
                const half8 al = *(const half8*)(pA2l + k0);
                const half8 b0h = *(const half8*)(Wout_hi + wo0 + k0);
                const half8 b0l = *(const half8*)(Wout_lo + wo0 + k0);
                const half8 b1h = *(const half8*)(Wout_hi + wo1 + k0);
                const half8 b1l = *(const half8*)(Wout_lo + wo1 + k0);
                aH[0] = __builtin_amdgcn_mfma_f32_16x16x32_f16(ah, b0h, aH[0], 0, 0, 0);
                aH[1] = __builtin_amdgcn_mfma_f32_16x16x32_f16(ah, b1h, aH[1], 0, 0, 0);
                aC[0] = __builtin_amdgcn_mfma_f32_16x16x32_f16(ah, b0l, aC[0], 0, 0, 0);
                aC[1] = __builtin_amdgcn_mfma_f32_16x16x32_f16(ah, b1l, aC[1], 0, 0, 0);
                aC[0] = __builtin_amdgcn_mfma_f32_16x16x32_f16(al, b0h, aC[0], 0, 0, 0);
                aC[1] = __builtin_amdgcn_mfma_f32_16x16x32_f16(al, b1h, aC[1], 0, 0, 0);
            }

            float* outT = out + (size_t)t * B_SZ * V_SZ;
            unsigned long long best[4] = {0ULL, 0ULL, 0ULL, 0ULL};
#pragma unroll
            for (int gn = 0; gn < 2; ++gn) {
                const int col = n0_2 + gn * 16 + lm;
                const float bo = gn ? bo1 : bo0;
#pragma unroll
                for (int r = 0; r < 4; ++r) {
                    const float v = aH[gn][r] + aC[gn][r] * (1.f / 2048.f) + bo;
                    const int row = m0_2 + kq * 4 + r;
                    __builtin_nontemporal_store(v, &outT[(size_t)row * V_SZ + col]);
                    const unsigned long long p = pack_vc(v, col);
                    if (p > best[r]) best[r] = p;
                }
            }
#pragma unroll
            for (int r = 0; r < 4; ++r) {
#pragma unroll
                for (int off = 1; off < 16; off <<= 1) {
                    const unsigned long long o = __shfl_xor(best[r], off);
                    if (o > best[r]) best[r] = o;
                }
            }
            if (lm == 0) {
#pragma unroll
                for (int r = 0; r < 4; ++r)
                    atomicMax(&tok_nxt[m0_2 + kq * 4 + r], best[r]);
            }
        }

        grid_barrier(bar_cnt, bar_gen);
    }
}

// ---------------------------------------------------------------------------
extern "C" void kernel_launch(void* const* d_in, const int* in_sizes, int n_in,
                              void* d_out, int out_size, void* d_ws, size_t ws_size,
                              hipStream_t stream)
{
    const float* enc_h = (const float*)d_in[2];
    const float* enc_c = (const float*)d_in[3];
    const float* emb   = (const float*)d_in[4];
    const float* W_ih  = (const float*)d_in[5];
    const float* W_hh  = (const float*)d_in[6];
    const float* b_ih  = (const float*)d_in[7];
    const float* b_hh  = (const float*)d_in[8];
    const float* W_out = (const float*)d_in[9];
    const float* b_out = (const float*)d_in[10];
    float* out = (float*)d_out;

    // workspace layout
    char* ws = (char*)d_ws;
    _Float16* Whh_hi  = (_Float16*)(ws);                          // 2 MB
    _Float16* Whh_lo  = (_Float16*)(ws + (2u << 20));             // 2 MB
    _Float16* Wout_hi = (_Float16*)(ws + (4u << 20));             // 0.5 MB
    _Float16* Wout_lo = (_Float16*)(ws + (4u << 20) + (512u << 10));
    _Float16* H0hi = (_Float16*)(ws + (5u << 20));
    _Float16* H0lo = (_Float16*)(ws + (6u << 20));
    _Float16* H1hi = (_Float16*)(ws + (7u << 20));
    _Float16* H1lo = (_Float16*)(ws + (8u << 20));
    float* cbuf = (float*)(ws + (9u << 20));                      // 2 MB
    float* Eg   = (float*)(ws + (11u << 20));                     // 4 MB
    unsigned long long* tokbuf = (unsigned long long*)(ws + (15u << 20)); // 16 KB
    unsigned* bar = (unsigned*)(ws + (15u << 20) + (64u << 10));  // 2 words

    const dim3 blk256(256);

    // one-time conversions + init
    cvt_pair<<<(G_SZ * H_SZ) / 1024, blk256, 0, stream>>>(W_hh, Whh_hi, Whh_lo);
    cvt_pair<<<(V_SZ * H_SZ) / 1024, blk256, 0, stream>>>(W_out, Wout_hi, Wout_lo);
    cvt_pair<<<(B_SZ * H_SZ) / 1024, blk256, 0, stream>>>(enc_h, H0hi, H0lo);
    hipMemcpyAsync(cbuf, enc_c, (size_t)B_SZ * H_SZ * 4, hipMemcpyDeviceToDevice, stream);
    init_state<<<8, blk256, 0, stream>>>(tokbuf, bar);

    // E_gates = emb @ W_ih^T + (b_ih + b_hh)   [V x 4H], fp32, once
    gemm_nt_f32<<<dim3(G_SZ / 64, V_SZ / 64), blk256, 0, stream>>>(
        emb, W_ih, Eg, V_SZ, G_SZ, H_SZ, b_ih, b_hh);

    // persistent kernel: all 64 steps, hand-rolled grid barrier
    persistent_decoder<<<dim3(N_BLOCKS), blk256, 0, stream>>>(
        Whh_hi, Whh_lo, Wout_hi, Wout_lo, Eg, b_out,
        H0hi, H0lo, H1hi, H1lo, cbuf, tokbuf, bar, out);
}